// Round 5
// baseline (489.699 us; speedup 1.0000x reference)
//
#include <hip/hip_runtime.h>
#include <hip/hip_bf16.h>

// Word2Vec NCE loss — INVERTED layout:
//   emb_out (480 MB, doesn't fit L3) is STREAMED one wave per vocab row;
//   emb_in  (16384 rows = 19.7 MB, L3-resident) is gathered per reference.
// Inverted index built on the fly: counts -> exclusive scan -> scatter of
// pair ids (b<<6|r) into per-row buckets. Each pair's logsig lands in its own
// result slot -> bitwise deterministic despite atomic bucket fill order.

#define D_DIM 300
#define D4    75     // float4 per row
#define C_DIM 10
#define NEG_DIM 50   // C*K
#define ROWS 60      // C + C*K

__device__ __forceinline__ float log_sigmoid_fast(float x) {
    float e = __expf(-fabsf(x));
    return fminf(x, 0.f) - __logf(1.f + e);
}

// ---------------- inverted-index build ----------------

__global__ __launch_bounds__(256) void k_init(int* __restrict__ counts,
                                              int* __restrict__ cursor, int V) {
    for (int i = blockIdx.x * 256 + threadIdx.x; i < V; i += gridDim.x * 256) {
        counts[i] = 0;
        cursor[i] = 0;
    }
}

__global__ __launch_bounds__(256) void k_count(const int* __restrict__ ctx,
                                               const int* __restrict__ negs,
                                               int* __restrict__ counts, int P) {
    int p = blockIdx.x * 256 + threadIdx.x;
    if (p >= P) return;
    int b = p / ROWS, r = p - b * ROWS;
    int v = (r < C_DIM) ? ctx[b * C_DIM + r] : negs[b * NEG_DIM + (r - C_DIM)];
    atomicAdd(&counts[v], 1);
}

// block sums over 1024-element chunks
__global__ __launch_bounds__(256) void k_scan1(const int* __restrict__ counts,
                                               int* __restrict__ bsum, int V) {
    __shared__ int s[256];
    const int base = blockIdx.x * 1024;
    const int t = threadIdx.x;
    int a = 0;
    #pragma unroll
    for (int j = 0; j < 4; ++j) {
        int i = base + 4 * t + j;
        if (i < V) a += counts[i];
    }
    s[t] = a; __syncthreads();
    for (int off = 128; off > 0; off >>= 1) {
        if (t < off) s[t] += s[t + off];
        __syncthreads();
    }
    if (t == 0) bsum[blockIdx.x] = s[0];
}

// exclusive scan of block sums (nb <= 512), 1 block of 512 threads
__global__ __launch_bounds__(512) void k_scan2(const int* __restrict__ bsum,
                                               int* __restrict__ boff, int nb) {
    __shared__ int s[512];
    const int t = threadIdx.x;
    int v = (t < nb) ? bsum[t] : 0;
    s[t] = v; __syncthreads();
    for (int off = 1; off < 512; off <<= 1) {
        int add = (t >= off) ? s[t - off] : 0;
        __syncthreads();
        s[t] += add;
        __syncthreads();
    }
    if (t < nb) boff[t] = s[t] - v;
}

// per-chunk exclusive scan + chunk offset -> global offsets
__global__ __launch_bounds__(256) void k_scan3(const int* __restrict__ counts,
                                               const int* __restrict__ boff,
                                               int* __restrict__ off, int V) {
    __shared__ int s[256];
    const int base = blockIdx.x * 1024;
    const int t = threadIdx.x;
    int c[4]; int a = 0;
    #pragma unroll
    for (int j = 0; j < 4; ++j) {
        int i = base + 4 * t + j;
        c[j] = (i < V) ? counts[i] : 0;
        a += c[j];
    }
    s[t] = a; __syncthreads();
    for (int o = 1; o < 256; o <<= 1) {
        int add = (t >= o) ? s[t - o] : 0;
        __syncthreads();
        s[t] += add;
        __syncthreads();
    }
    int run = boff[blockIdx.x] + s[t] - a;   // exclusive prefix for this thread
    #pragma unroll
    for (int j = 0; j < 4; ++j) {
        int i = base + 4 * t + j;
        if (i < V) off[i] = run;
        run += c[j];
    }
}

__global__ __launch_bounds__(256) void k_scatter(const int* __restrict__ ctx,
                                                 const int* __restrict__ negs,
                                                 const int* __restrict__ off,
                                                 int* __restrict__ cursor,
                                                 int* __restrict__ bucket, int P) {
    int p = blockIdx.x * 256 + threadIdx.x;
    if (p >= P) return;
    int b = p / ROWS, r = p - b * ROWS;
    int v = (r < C_DIM) ? ctx[b * C_DIM + r] : negs[b * NEG_DIM + (r - C_DIM)];
    int pos = off[v] + atomicAdd(&cursor[v], 1);
    bucket[pos] = (b << 6) | r;
}

// ---------------- main: stream emb_out, gather emb_in ----------------

__global__ __launch_bounds__(256) void k_main(
    const int*   __restrict__ target,
    const float* __restrict__ emb_in,
    const float* __restrict__ emb_out,
    const int*   __restrict__ counts,
    const int*   __restrict__ off,
    const int*   __restrict__ bucket,
    float*       __restrict__ result)
{
    const int tid  = threadIdx.x;
    const int lane = tid & 63;
    const int wave = tid >> 6;
    const int v    = blockIdx.x * 4 + wave;

    const int n = counts[v];
    if (n == 0) return;
    const int base = off[v];

    const bool tail = lane < (D4 - 64);   // lanes 0..10
    const float4 zero = make_float4(0.f, 0.f, 0.f, 0.f);

    // stream this vocab row into registers
    const float4* orow = reinterpret_cast<const float4*>(emb_out + (size_t)v * D_DIM);
    float4 oa = orow[lane];
    float4 ob = tail ? orow[64 + lane] : zero;

    // prefetch all bucket entries + their targets in one shot (n <= 64 common)
    int eAll = (lane < n) ? bucket[base + lane] : 0;
    int tAll = (lane < n) ? target[eAll >> 6] : 0;

    // 1-deep pipeline over pairs
    int e = __builtin_amdgcn_readlane(eAll, 0);
    int t = __builtin_amdgcn_readlane(tAll, 0);
    const float4* trow = reinterpret_cast<const float4*>(emb_in + (size_t)t * D_DIM);
    float4 ta = trow[lane];
    float4 tb = tail ? trow[64 + lane] : zero;

    for (int k = 0; k < n; ++k) {
        int e1 = 0;
        float4 na = zero, nb_ = zero;
        if (k + 1 < n) {
            int t1;
            if (k + 1 < 64) {
                e1 = __builtin_amdgcn_readlane(eAll, k + 1);
                t1 = __builtin_amdgcn_readlane(tAll, k + 1);
            } else {                 // pathological bucket > 64
                e1 = bucket[base + k + 1];
                t1 = target[e1 >> 6];
            }
            const float4* tr = reinterpret_cast<const float4*>(emb_in + (size_t)t1 * D_DIM);
            na  = tr[lane];
            nb_ = tail ? tr[64 + lane] : zero;
        }

        float dot = oa.x * ta.x + oa.y * ta.y + oa.z * ta.z + oa.w * ta.w
                  + ob.x * tb.x + ob.y * tb.y + ob.z * tb.z + ob.w * tb.w;
        #pragma unroll
        for (int o = 32; o > 0; o >>= 1)
            dot += __shfl_xor(dot, o, 64);

        const float x = ((e & 63) < C_DIM) ? dot : -dot;
        const float ls = log_sigmoid_fast(x);
        if (lane == 0) result[e] = ls;

        e = e1; ta = na; tb = nb_;
    }
}

// ---------------- reduction ----------------

__global__ __launch_bounds__(256) void k_r1(const float* __restrict__ res,
                                            float* __restrict__ part, int n) {
    __shared__ float s[256];
    float a = 0.f;
    for (int i = blockIdx.x * 256 + threadIdx.x; i < n; i += 1024 * 256) {
        if ((i & 63) < ROWS) a += res[i];
    }
    s[threadIdx.x] = a; __syncthreads();
    for (int o = 128; o > 0; o >>= 1) {
        if (threadIdx.x < o) s[threadIdx.x] += s[threadIdx.x + o];
        __syncthreads();
    }
    if (threadIdx.x == 0) part[blockIdx.x] = s[0];
}

__global__ __launch_bounds__(256) void k_r2(const float* __restrict__ part,
                                            float* __restrict__ out,
                                            int n, float inv_scale) {
    __shared__ float s[256];
    float a = 0.f;
    for (int i = threadIdx.x; i < n; i += 256) a += part[i];
    s[threadIdx.x] = a; __syncthreads();
    for (int o = 128; o > 0; o >>= 1) {
        if (threadIdx.x < o) s[threadIdx.x] += s[threadIdx.x + o];
        __syncthreads();
    }
    if (threadIdx.x == 0) out[0] = -s[0] * inv_scale;
}

// ---------------- fallback (round-3 path) ----------------

__global__ __launch_bounds__(256) void w2v_loss_partial(
    const int* __restrict__ target, const int* __restrict__ context,
    const int* __restrict__ negs, const float* __restrict__ emb_in,
    const float* __restrict__ emb_out, float* __restrict__ partial)
{
    const int tid = threadIdx.x, lane = tid & 63, wave = tid >> 6;
    const int b = blockIdx.x * 4 + wave;
    int v_idx = 0;
    if (lane < C_DIM)     v_idx = context[b * C_DIM + lane];
    else if (lane < ROWS) v_idx = negs[b * NEG_DIM + (lane - C_DIM)];
    const float4* trow = reinterpret_cast<const float4*>(emb_in + (size_t)target[b] * D_DIM);
    const bool tail = lane < (D4 - 64);
    float4 ta = trow[lane];
    float4 tb = make_float4(0.f, 0.f, 0.f, 0.f);
    if (tail) tb = trow[64 + lane];
    float acc = 0.f;
    #pragma unroll 3
    for (int g = 0; g < ROWS / 4; ++g) {
        float d[4];
        #pragma unroll
        for (int i = 0; i < 4; ++i) {
            const int sidx = __builtin_amdgcn_readlane(v_idx, g * 4 + i);
            const float4* row = reinterpret_cast<const float4*>(emb_out + (size_t)sidx * D_DIM);
            float4 ra = row[lane];
            float4 rb = make_float4(0.f, 0.f, 0.f, 0.f);
            if (tail) rb = row[64 + lane];
            d[i] = ra.x * ta.x + ra.y * ta.y + ra.z * ta.z + ra.w * ta.w
                 + rb.x * tb.x + rb.y * tb.y + rb.z * tb.z + rb.w * tb.w;
        }
        #pragma unroll
        for (int i = 0; i < 4; ++i) d[i] += __shfl_xor(d[i], 32, 64);
        const bool hi32 = (lane & 32) != 0;
        float p = hi32 ? d[1] : d[0];
        float q = hi32 ? d[3] : d[2];
        p += __shfl_xor(p, 16, 64);
        q += __shfl_xor(q, 16, 64);
        float vv = (lane & 16) ? q : p;
        vv += __shfl_xor(vv, 8, 64);
        vv += __shfl_xor(vv, 4, 64);
        vv += __shfl_xor(vv, 2, 64);
        vv += __shfl_xor(vv, 1, 64);
        const int gq = lane >> 4;
        const int rid = g * 4 + (((gq & 1) << 1) | (gq >> 1));
        acc += log_sigmoid_fast((rid < C_DIM) ? vv : -vv);
    }
    acc += __shfl_xor(acc, 16, 64);
    acc += __shfl_xor(acc, 32, 64);
    if (lane == 0) partial[b] = acc;
}

// ---------------- launch ----------------

extern "C" void kernel_launch(void* const* d_in, const int* in_sizes, int n_in,
                              void* d_out, int out_size, void* d_ws, size_t ws_size,
                              hipStream_t stream) {
    const int*   target  = (const int*)  d_in[0];
    const int*   context = (const int*)  d_in[1];
    const int*   negs    = (const int*)  d_in[2];
    const float* emb_in  = (const float*)d_in[3];
    const float* emb_out = (const float*)d_in[4];
    float*       out     = (float*)d_out;

    const int B = in_sizes[0];              // 16384
    const int V = in_sizes[3] / D_DIM;      // 400000
    const int P = B * ROWS;                 // 983040
    const int RSLOTS = B * 64;              // 1048576
    const int NB = (V + 1023) / 1024;       // 391 scan chunks
    const float inv_scale = 1.0f / ((float)B * (float)C_DIM);

    auto al = [](size_t x) { return (x + 255) & ~(size_t)255; };
    size_t o = 0;
    const size_t o_counts = o; o = al(o + (size_t)V * 4);
    const size_t o_off    = o; o = al(o + (size_t)V * 4);
    const size_t o_cur    = o; o = al(o + (size_t)V * 4);
    const size_t o_bsum   = o; o = al(o + 4096);
    const size_t o_boff   = o; o = al(o + 4096);
    const size_t o_bucket = o; o = al(o + (size_t)P * 4);
    const size_t o_res    = o; o = al(o + (size_t)RSLOTS * 4);
    const size_t o_part   = o; o = al(o + 1024 * 4);
    const size_t needed = o;

    char* ws = (char*)d_ws;
    if (ws_size >= needed && NB <= 512 && (V % 4) == 0) {
        int*   counts = (int*)(ws + o_counts);
        int*   offv   = (int*)(ws + o_off);
        int*   cursor = (int*)(ws + o_cur);
        int*   bsum   = (int*)(ws + o_bsum);
        int*   boff   = (int*)(ws + o_boff);
        int*   bucket = (int*)(ws + o_bucket);
        float* result = (float*)(ws + o_res);
        float* part   = (float*)(ws + o_part);

        k_init   <<<1024, 256, 0, stream>>>(counts, cursor, V);
        k_count  <<<(P + 255) / 256, 256, 0, stream>>>(context, negs, counts, P);
        k_scan1  <<<NB, 256, 0, stream>>>(counts, bsum, V);
        k_scan2  <<<1, 512, 0, stream>>>(bsum, boff, NB);
        k_scan3  <<<NB, 256, 0, stream>>>(counts, boff, offv, V);
        k_scatter<<<(P + 255) / 256, 256, 0, stream>>>(context, negs, offv,
                                                       cursor, bucket, P);
        k_main   <<<V / 4, 256, 0, stream>>>(target, emb_in, emb_out,
                                             counts, offv, bucket, result);
        k_r1     <<<1024, 256, 0, stream>>>(result, part, RSLOTS);
        k_r2     <<<1, 256, 0, stream>>>(part, out, 1024, inv_scale);
    } else {
        float* partial = (float*)d_ws;      // B floats
        w2v_loss_partial<<<B / 4, 256, 0, stream>>>(target, context, negs,
                                                    emb_in, emb_out, partial);
        k_r2<<<1, 256, 0, stream>>>(partial, out, B, inv_scale);
    }
}

// Round 6
// 294.959 us; speedup vs baseline: 1.6602x; 1.6602x over previous
//
#include <hip/hip_runtime.h>
#include <hip/hip_bf16.h>

// Word2Vec NCE loss, phased gather:
//   Phase p handles only emb_out rows in vocab range p (3 ranges, ~160 MB each,
//   fits the 256 MB L3 together with the 20 MB emb_in target working set), so
//   intra-batch row reuse (avg 2.46x) is all L3 hits and each unique emb_out
//   row is fetched from HBM exactly once (~437 MB compulsory vs 639 MB
//   unphased). A build kernel precomputes per-(b,phase) compacted row lists so
//   the phase kernel keeps full MLP (4 rows in flight, batched butterfly, no
//   data-dependent branches) -- fixing round 4's latency collapse.

#define D_DIM 300
#define D4    75     // float4 per row
#define C_DIM 10
#define NEG_DIM 50   // C*K
#define ROWS 60      // C + C*K
#define PHASES 3

__device__ __forceinline__ float log_sigmoid_fast(float x) {
    float e = __expf(-fabsf(x));
    return fminf(x, 0.f) - __logf(1.f + e);
}

// ---- build: per-(b,phase) compacted lists, entry = (v<<6)|r. No atomics. ----
__global__ __launch_bounds__(256) void k_build(
    const int* __restrict__ ctx, const int* __restrict__ negs,
    int* __restrict__ lists,   // [PHASES][B][ROWS]
    int* __restrict__ cnts,    // [PHASES][B]
    int B, int PQ)
{
    const int b = blockIdx.x * 256 + threadIdx.x;
    if (b >= B) return;
    int c0 = 0, c1 = 0, c2 = 0;
    #pragma unroll 4
    for (int r = 0; r < ROWS; ++r) {
        const int v = (r < C_DIM) ? ctx[b * C_DIM + r]
                                  : negs[b * NEG_DIM + (r - C_DIM)];
        const int p = v / PQ;   // 0..2
        int* slot;
        if (p == 0)      slot = &lists[((size_t)0 * B + b) * ROWS + c0++];
        else if (p == 1) slot = &lists[((size_t)1 * B + b) * ROWS + c1++];
        else             slot = &lists[((size_t)2 * B + b) * ROWS + c2++];
        *slot = (v << 6) | r;
    }
    cnts[0 * B + b] = c0;
    cnts[1 * B + b] = c1;
    cnts[2 * B + b] = c2;
}

// ---- phase kernel: wave per b, 4 rows per group, batched butterfly ----
__global__ __launch_bounds__(256) void k_phase(
    const int*   __restrict__ target,
    const float* __restrict__ emb_in,
    const float* __restrict__ emb_out,
    const int*   __restrict__ list,   // this phase: [B][ROWS]
    const int*   __restrict__ cnt,    // this phase: [B]
    float*       __restrict__ partial)
{
    const int tid  = threadIdx.x;
    const int lane = tid & 63;
    const int wave = tid >> 6;
    const int b    = blockIdx.x * 4 + wave;

    const int n = cnt[b];
    if (n == 0) { if (lane == 0) partial[b] = 0.f; return; }

    const float4 zero = make_float4(0.f, 0.f, 0.f, 0.f);
    const bool tail = lane < (D4 - 64);   // lanes 0..10

    // lane i holds list entry i; sentinel = row 0 (L1-hot), r=63 (masked)
    const int* lst = list + (size_t)b * ROWS;
    const int eAll = (lane < n) ? lst[lane] : 63;

    // target row in registers
    const float4* trow =
        reinterpret_cast<const float4*>(emb_in + (size_t)target[b] * D_DIM);
    float4 ta = trow[lane];
    float4 tb = tail ? trow[64 + lane] : zero;

    float acc = 0.f;
    const int ng = (n + 3) >> 2;
    #pragma unroll 2
    for (int g = 0; g < ng; ++g) {
        const int e0 = __builtin_amdgcn_readlane(eAll, 4 * g + 0);
        const int e1 = __builtin_amdgcn_readlane(eAll, 4 * g + 1);
        const int e2 = __builtin_amdgcn_readlane(eAll, 4 * g + 2);
        const int e3 = __builtin_amdgcn_readlane(eAll, 4 * g + 3);

        float d[4];
        {
            const float4* r0 = reinterpret_cast<const float4*>(emb_out + (size_t)(e0 >> 6) * D_DIM);
            const float4* r1 = reinterpret_cast<const float4*>(emb_out + (size_t)(e1 >> 6) * D_DIM);
            const float4* r2 = reinterpret_cast<const float4*>(emb_out + (size_t)(e2 >> 6) * D_DIM);
            const float4* r3 = reinterpret_cast<const float4*>(emb_out + (size_t)(e3 >> 6) * D_DIM);
            float4 a0 = r0[lane], b0 = tail ? r0[64 + lane] : zero;
            float4 a1 = r1[lane], b1 = tail ? r1[64 + lane] : zero;
            float4 a2 = r2[lane], b2 = tail ? r2[64 + lane] : zero;
            float4 a3 = r3[lane], b3 = tail ? r3[64 + lane] : zero;
            d[0] = a0.x*ta.x + a0.y*ta.y + a0.z*ta.z + a0.w*ta.w
                 + b0.x*tb.x + b0.y*tb.y + b0.z*tb.z + b0.w*tb.w;
            d[1] = a1.x*ta.x + a1.y*ta.y + a1.z*ta.z + a1.w*ta.w
                 + b1.x*tb.x + b1.y*tb.y + b1.z*tb.z + b1.w*tb.w;
            d[2] = a2.x*ta.x + a2.y*ta.y + a2.z*ta.z + a2.w*ta.w
                 + b2.x*tb.x + b2.y*tb.y + b2.z*tb.z + b2.w*tb.w;
            d[3] = a3.x*ta.x + a3.y*ta.y + a3.z*ta.z + a3.w*ta.w
                 + b3.x*tb.x + b3.y*tb.y + b3.z*tb.z + b3.w*tb.w;
        }

        // batched butterfly: 16-lane group gq ends with element perm(gq)={0,2,1,3}
        #pragma unroll
        for (int i = 0; i < 4; ++i) d[i] += __shfl_xor(d[i], 32, 64);
        const bool hi32 = (lane & 32) != 0;
        float p = hi32 ? d[1] : d[0];
        float q = hi32 ? d[3] : d[2];
        p += __shfl_xor(p, 16, 64);
        q += __shfl_xor(q, 16, 64);
        float vv = (lane & 16) ? q : p;
        vv += __shfl_xor(vv, 8, 64);
        vv += __shfl_xor(vv, 4, 64);
        vv += __shfl_xor(vv, 2, 64);
        vv += __shfl_xor(vv, 1, 64);

        const int gq = lane >> 4;
        const int rsel = (gq == 0) ? (e0 & 63)
                       : (gq == 1) ? (e2 & 63)
                       : (gq == 2) ? (e1 & 63)
                                   : (e3 & 63);
        const float x = (rsel < C_DIM) ? vv : -vv;
        acc += (rsel < ROWS) ? log_sigmoid_fast(x) : 0.f;
    }

    acc += __shfl_xor(acc, 16, 64);
    acc += __shfl_xor(acc, 32, 64);
    if (lane == 0) partial[b] = acc;
}

// ---- final reduce ----
__global__ __launch_bounds__(256) void k_r2(const float* __restrict__ part,
                                            float* __restrict__ out,
                                            int n, float inv_scale) {
    __shared__ float s[256];
    float a = 0.f;
    for (int i = threadIdx.x; i < n; i += 256) a += part[i];
    s[threadIdx.x] = a; __syncthreads();
    for (int o = 128; o > 0; o >>= 1) {
        if (threadIdx.x < o) s[threadIdx.x] += s[threadIdx.x + o];
        __syncthreads();
    }
    if (threadIdx.x == 0) out[0] = -s[0] * inv_scale;
}

// ---- fallback (round-3 path, unphased) ----
__global__ __launch_bounds__(256) void w2v_loss_partial(
    const int* __restrict__ target, const int* __restrict__ context,
    const int* __restrict__ negs, const float* __restrict__ emb_in,
    const float* __restrict__ emb_out, float* __restrict__ partial)
{
    const int tid = threadIdx.x, lane = tid & 63, wave = tid >> 6;
    const int b = blockIdx.x * 4 + wave;
    int v_idx = 0;
    if (lane < C_DIM)     v_idx = context[b * C_DIM + lane];
    else if (lane < ROWS) v_idx = negs[b * NEG_DIM + (lane - C_DIM)];
    const float4* trow = reinterpret_cast<const float4*>(emb_in + (size_t)target[b] * D_DIM);
    const bool tail = lane < (D4 - 64);
    float4 ta = trow[lane];
    float4 tb = make_float4(0.f, 0.f, 0.f, 0.f);
    if (tail) tb = trow[64 + lane];
    float acc = 0.f;
    #pragma unroll 3
    for (int g = 0; g < ROWS / 4; ++g) {
        float d[4];
        #pragma unroll
        for (int i = 0; i < 4; ++i) {
            const int sidx = __builtin_amdgcn_readlane(v_idx, g * 4 + i);
            const float4* row = reinterpret_cast<const float4*>(emb_out + (size_t)sidx * D_DIM);
            float4 ra = row[lane];
            float4 rb = make_float4(0.f, 0.f, 0.f, 0.f);
            if (tail) rb = row[64 + lane];
            d[i] = ra.x * ta.x + ra.y * ta.y + ra.z * ta.z + ra.w * ta.w
                 + rb.x * tb.x + rb.y * tb.y + rb.z * tb.z + rb.w * tb.w;
        }
        #pragma unroll
        for (int i = 0; i < 4; ++i) d[i] += __shfl_xor(d[i], 32, 64);
        const bool hi32 = (lane & 32) != 0;
        float p = hi32 ? d[1] : d[0];
        float q = hi32 ? d[3] : d[2];
        p += __shfl_xor(p, 16, 64);
        q += __shfl_xor(q, 16, 64);
        float vv = (lane & 16) ? q : p;
        vv += __shfl_xor(vv, 8, 64);
        vv += __shfl_xor(vv, 4, 64);
        vv += __shfl_xor(vv, 2, 64);
        vv += __shfl_xor(vv, 1, 64);
        const int gq = lane >> 4;
        const int rid = g * 4 + (((gq & 1) << 1) | (gq >> 1));
        acc += log_sigmoid_fast((rid < C_DIM) ? vv : -vv);
    }
    acc += __shfl_xor(acc, 16, 64);
    acc += __shfl_xor(acc, 32, 64);
    if (lane == 0) partial[b] = acc;
}

// ---- launch ----
extern "C" void kernel_launch(void* const* d_in, const int* in_sizes, int n_in,
                              void* d_out, int out_size, void* d_ws, size_t ws_size,
                              hipStream_t stream) {
    const int*   target  = (const int*)  d_in[0];
    const int*   context = (const int*)  d_in[1];
    const int*   negs    = (const int*)  d_in[2];
    const float* emb_in  = (const float*)d_in[3];
    const float* emb_out = (const float*)d_in[4];
    float*       out     = (float*)d_out;

    const int B  = in_sizes[0];                 // 16384
    const int V  = in_sizes[3] / D_DIM;         // 400000
    const int PQ = (V + PHASES - 1) / PHASES;   // vocab range per phase
    const float inv_scale = 1.0f / ((float)B * (float)C_DIM);

    auto al = [](size_t x) { return (x + 255) & ~(size_t)255; };
    size_t o = 0;
    const size_t o_lists = o; o = al(o + (size_t)PHASES * B * ROWS * 4);
    const size_t o_cnts  = o; o = al(o + (size_t)PHASES * B * 4);
    const size_t o_part  = o; o = al(o + (size_t)PHASES * B * 4);
    const size_t needed  = o;

    char* ws = (char*)d_ws;
    if (ws_size >= needed && (B % 4) == 0) {
        int*   lists = (int*)(ws + o_lists);
        int*   cnts  = (int*)(ws + o_cnts);
        float* part  = (float*)(ws + o_part);

        k_build<<<(B + 255) / 256, 256, 0, stream>>>(context, negs, lists,
                                                     cnts, B, PQ);
        for (int p = 0; p < PHASES; ++p) {
            k_phase<<<B / 4, 256, 0, stream>>>(
                target, emb_in, emb_out,
                lists + (size_t)p * B * ROWS,
                cnts  + (size_t)p * B,
                part  + (size_t)p * B);
        }
        k_r2<<<1, 256, 0, stream>>>(part, out, PHASES * B, inv_scale);
    } else {
        float* partial = (float*)d_ws;          // B floats
        w2v_loss_partial<<<B / 4, 256, 0, stream>>>(target, context, negs,
                                                    emb_in, emb_out, partial);
        k_r2<<<1, 256, 0, stream>>>(partial, out, B, inv_scale);
    }
}

// Round 7
// 220.347 us; speedup vs baseline: 2.2224x; 1.3386x over previous
//
#include <hip/hip_runtime.h>
#include <hip/hip_bf16.h>

// Word2Vec NCE loss — round-3 structure (wave per b, 4-row groups, batched
// butterfly, one logsig per 4 rows) + EXPLICIT 1-deep software pipeline:
// next group's 8 float4 row-loads are issued before the current group's
// reduce, so ~8 vmem loads stay in flight per wave (VGPR-backed), attacking
// the random-gather latency wall. No phasing (3 attempts all regressed).

#define D_DIM 300
#define D4    75     // float4 per row
#define C_DIM 10
#define NEG_DIM 50   // C*K
#define ROWS 60      // C + C*K
#define NG    15     // ROWS/4 groups

__device__ __forceinline__ float log_sigmoid_fast(float x) {
    float e = __expf(-fabsf(x));
    return fminf(x, 0.f) - __logf(1.f + e);
}

__global__ __launch_bounds__(256) void w2v_loss_partial(
    const int*   __restrict__ target,
    const int*   __restrict__ context,
    const int*   __restrict__ negs,
    const float* __restrict__ emb_in,
    const float* __restrict__ emb_out,
    float*       __restrict__ partial)
{
    const int tid  = threadIdx.x;
    const int lane = tid & 63;
    const int wave = tid >> 6;
    const int b    = blockIdx.x * 4 + wave;

    // lane r (<60) holds gather index of row r
    int v_idx = 0;
    if (lane < C_DIM)      v_idx = context[b * C_DIM + lane];
    else if (lane < ROWS)  v_idx = negs[b * NEG_DIM + (lane - C_DIM)];

    const float4 zero = make_float4(0.f, 0.f, 0.f, 0.f);
    const bool tail = lane < (D4 - 64);   // lanes 0..10

    // target row in registers: lane j holds float4 j and (64+j)
    const float4* trow =
        reinterpret_cast<const float4*>(emb_in + (size_t)target[b] * D_DIM);
    float4 ta = trow[lane];
    float4 tb = tail ? trow[64 + lane] : zero;

    // ---- software pipeline: load group g+1 while reducing group g ----
    float4 A0, A1, A2, A3, B0, B1, B2, B3;

    {   // prologue: group 0
        const float4* r0 = reinterpret_cast<const float4*>(emb_out + (size_t)__builtin_amdgcn_readlane(v_idx, 0) * D_DIM);
        const float4* r1 = reinterpret_cast<const float4*>(emb_out + (size_t)__builtin_amdgcn_readlane(v_idx, 1) * D_DIM);
        const float4* r2 = reinterpret_cast<const float4*>(emb_out + (size_t)__builtin_amdgcn_readlane(v_idx, 2) * D_DIM);
        const float4* r3 = reinterpret_cast<const float4*>(emb_out + (size_t)__builtin_amdgcn_readlane(v_idx, 3) * D_DIM);
        A0 = r0[lane]; B0 = tail ? r0[64 + lane] : zero;
        A1 = r1[lane]; B1 = tail ? r1[64 + lane] : zero;
        A2 = r2[lane]; B2 = tail ? r2[64 + lane] : zero;
        A3 = r3[lane]; B3 = tail ? r3[64 + lane] : zero;
    }

    float acc = 0.f;
    #pragma unroll
    for (int g = 0; g < NG; ++g) {
        // issue next group's loads first (independent of current compute)
        float4 N0, N1, N2, N3, M0, M1, M2, M3;
        if (g + 1 < NG) {
            const int base = 4 * (g + 1);
            const float4* r0 = reinterpret_cast<const float4*>(emb_out + (size_t)__builtin_amdgcn_readlane(v_idx, base + 0) * D_DIM);
            const float4* r1 = reinterpret_cast<const float4*>(emb_out + (size_t)__builtin_amdgcn_readlane(v_idx, base + 1) * D_DIM);
            const float4* r2 = reinterpret_cast<const float4*>(emb_out + (size_t)__builtin_amdgcn_readlane(v_idx, base + 2) * D_DIM);
            const float4* r3 = reinterpret_cast<const float4*>(emb_out + (size_t)__builtin_amdgcn_readlane(v_idx, base + 3) * D_DIM);
            N0 = r0[lane]; M0 = tail ? r0[64 + lane] : zero;
            N1 = r1[lane]; M1 = tail ? r1[64 + lane] : zero;
            N2 = r2[lane]; M2 = tail ? r2[64 + lane] : zero;
            N3 = r3[lane]; M3 = tail ? r3[64 + lane] : zero;
        }

        float d[4];
        d[0] = A0.x*ta.x + A0.y*ta.y + A0.z*ta.z + A0.w*ta.w
             + B0.x*tb.x + B0.y*tb.y + B0.z*tb.z + B0.w*tb.w;
        d[1] = A1.x*ta.x + A1.y*ta.y + A1.z*ta.z + A1.w*ta.w
             + B1.x*tb.x + B1.y*tb.y + B1.z*tb.z + B1.w*tb.w;
        d[2] = A2.x*ta.x + A2.y*ta.y + A2.z*ta.z + A2.w*ta.w
             + B2.x*tb.x + B2.y*tb.y + B2.z*tb.z + B2.w*tb.w;
        d[3] = A3.x*ta.x + A3.y*ta.y + A3.z*ta.z + A3.w*ta.w
             + B3.x*tb.x + B3.y*tb.y + B3.z*tb.z + B3.w*tb.w;

        // batched butterfly: 16-lane group gq ends with row 4g + perm(gq),
        // perm = {0,2,1,3}  (verified absmax==0 in rounds 2-3)
        #pragma unroll
        for (int i = 0; i < 4; ++i) d[i] += __shfl_xor(d[i], 32, 64);
        const bool hi32 = (lane & 32) != 0;
        float p = hi32 ? d[1] : d[0];
        float q = hi32 ? d[3] : d[2];
        p += __shfl_xor(p, 16, 64);
        q += __shfl_xor(q, 16, 64);
        float vv = (lane & 16) ? q : p;
        vv += __shfl_xor(vv, 8, 64);
        vv += __shfl_xor(vv, 4, 64);
        vv += __shfl_xor(vv, 2, 64);
        vv += __shfl_xor(vv, 1, 64);

        const int gq  = lane >> 4;
        const int rid = g * 4 + (((gq & 1) << 1) | (gq >> 1));
        acc += log_sigmoid_fast((rid < C_DIM) ? vv : -vv);

        A0 = N0; A1 = N1; A2 = N2; A3 = N3;
        B0 = M0; B1 = M1; B2 = M2; B3 = M3;
    }

    // combine the 4 group-accumulators (each replicated 16x)
    acc += __shfl_xor(acc, 16, 64);
    acc += __shfl_xor(acc, 32, 64);
    if (lane == 0) partial[b] = acc;
}

__global__ __launch_bounds__(1024) void w2v_loss_reduce(
    const float* __restrict__ partial,
    float*       __restrict__ out,
    int n, float inv_scale)
{
    __shared__ float s[1024];
    float acc = 0.f;
    for (int i = threadIdx.x; i < n; i += 1024) acc += partial[i];
    s[threadIdx.x] = acc;
    __syncthreads();
    #pragma unroll
    for (int off = 512; off > 0; off >>= 1) {
        if (threadIdx.x < off) s[threadIdx.x] += s[threadIdx.x + off];
        __syncthreads();
    }
    if (threadIdx.x == 0) out[0] = -s[0] * inv_scale;
}

extern "C" void kernel_launch(void* const* d_in, const int* in_sizes, int n_in,
                              void* d_out, int out_size, void* d_ws, size_t ws_size,
                              hipStream_t stream) {
    const int*   target  = (const int*)  d_in[0];
    const int*   context = (const int*)  d_in[1];
    const int*   negs    = (const int*)  d_in[2];
    const float* emb_in  = (const float*)d_in[3];
    const float* emb_out = (const float*)d_in[4];
    float*       out     = (float*)d_out;

    const int B = in_sizes[0];              // 16384
    float* partial = (float*)d_ws;          // B floats

    w2v_loss_partial<<<B / 4, 256, 0, stream>>>(target, context, negs,
                                                emb_in, emb_out, partial);
    const float inv_scale = 1.0f / ((float)B * (float)C_DIM);
    w2v_loss_reduce<<<1, 1024, 0, stream>>>(partial, out, B, inv_scale);
}

// Round 8
// 192.357 us; speedup vs baseline: 2.5458x; 1.1455x over previous
//
#include <hip/hip_runtime.h>
#include <hip/hip_bf16.h>

// Word2Vec NCE loss — FINAL (round-3 structure, empirically best at ~210 us).
//   B=16384, C=10, K=5, V=400000, D=300 fp32.
// One wave per batch element; 60 gather rows in 15 groups of 4; batched
// butterfly (10 shfl / 4 rows) leaves each 16-lane group holding one row's
// dot -> one logsig evaluation covers 4 rows. Target row register-resident.
//
// Why this is the roofline: HBM demand = 639 MB (measured FETCH; L3 absorbs
// ~560 MB of the 1.18 GB logical gather) delivered at ~3.1 TB/s — the
// achievable rate for random 1.2 KB-row reads (~2x row-activate penalty vs
// the 6.3 TB/s streaming ceiling). 639 MB / 3.1 TB/s ~= 205 us. Measured
// alternatives: vocab-phasing (R4: 277, R6: 295), inverted streaming
// (R5: 490), deeper SW pipeline (R7: 220) — all regressed.

#define D_DIM 300
#define D4    75     // float4 per row
#define C_DIM 10
#define NEG_DIM 50   // C*K
#define ROWS 60      // C + C*K

__device__ __forceinline__ float log_sigmoid_fast(float x) {
    float e = __expf(-fabsf(x));
    return fminf(x, 0.f) - __logf(1.f + e);
}

__global__ __launch_bounds__(256) void w2v_loss_partial(
    const int*   __restrict__ target,
    const int*   __restrict__ context,
    const int*   __restrict__ negs,
    const float* __restrict__ emb_in,
    const float* __restrict__ emb_out,
    float*       __restrict__ partial)
{
    const int tid  = threadIdx.x;
    const int lane = tid & 63;
    const int wave = tid >> 6;
    const int b    = blockIdx.x * 4 + wave;

    // lane r (<60) holds gather index of row r
    int v_idx = 0;
    if (lane < C_DIM)      v_idx = context[b * C_DIM + lane];
    else if (lane < ROWS)  v_idx = negs[b * NEG_DIM + (lane - C_DIM)];

    // target row in registers: lane j holds float4 j and (64+j)
    const float4* trow =
        reinterpret_cast<const float4*>(emb_in + (size_t)target[b] * D_DIM);
    const bool tail = lane < (D4 - 64);   // lanes 0..10
    float4 ta = trow[lane];
    float4 tb = make_float4(0.f, 0.f, 0.f, 0.f);
    if (tail) tb = trow[64 + lane];

    float acc = 0.f;
    #pragma unroll 3
    for (int g = 0; g < ROWS / 4; ++g) {
        float d[4];
        #pragma unroll
        for (int i = 0; i < 4; ++i) {
            const int sidx = __builtin_amdgcn_readlane(v_idx, g * 4 + i); // uniform
            const float4* row =
                reinterpret_cast<const float4*>(emb_out + (size_t)sidx * D_DIM);
            float4 ra = row[lane];
            float4 rb = make_float4(0.f, 0.f, 0.f, 0.f);
            if (tail) rb = row[64 + lane];
            d[i] = ra.x * ta.x + ra.y * ta.y + ra.z * ta.z + ra.w * ta.w
                 + rb.x * tb.x + rb.y * tb.y + rb.z * tb.z + rb.w * tb.w;
        }

        // batched 4-row butterfly: each 16-lane group ends with one row's sum
        #pragma unroll
        for (int i = 0; i < 4; ++i) d[i] += __shfl_xor(d[i], 32, 64);
        const bool hi32 = (lane & 32) != 0;
        float p = hi32 ? d[1] : d[0];
        float q = hi32 ? d[3] : d[2];
        p += __shfl_xor(p, 16, 64);
        q += __shfl_xor(q, 16, 64);
        float v = (lane & 16) ? q : p;
        v += __shfl_xor(v, 8, 64);
        v += __shfl_xor(v, 4, 64);
        v += __shfl_xor(v, 2, 64);
        v += __shfl_xor(v, 1, 64);

        // 16-lane group (lane>>4) holds row g*4 + perm, perm = {0,2,1,3}
        const int gq  = lane >> 4;
        const int rid = g * 4 + (((gq & 1) << 1) | (gq >> 1));
        const float x = (rid < C_DIM) ? v : -v;
        acc += log_sigmoid_fast(x);
    }

    // combine the 4 group-accumulators (each replicated 16x)
    acc += __shfl_xor(acc, 16, 64);
    acc += __shfl_xor(acc, 32, 64);
    if (lane == 0) partial[b] = acc;
}

__global__ __launch_bounds__(1024) void w2v_loss_reduce(
    const float* __restrict__ partial,
    float*       __restrict__ out,
    int n, float inv_scale)
{
    __shared__ float s[1024];
    float acc = 0.f;
    for (int i = threadIdx.x; i < n; i += 1024) acc += partial[i];
    s[threadIdx.x] = acc;
    __syncthreads();
    #pragma unroll
    for (int off = 512; off > 0; off >>= 1) {
        if (threadIdx.x < off) s[threadIdx.x] += s[threadIdx.x + off];
        __syncthreads();
    }
    if (threadIdx.x == 0) out[0] = -s[0] * inv_scale;
}

extern "C" void kernel_launch(void* const* d_in, const int* in_sizes, int n_in,
                              void* d_out, int out_size, void* d_ws, size_t ws_size,
                              hipStream_t stream) {
    const int*   target  = (const int*)  d_in[0];
    const int*   context = (const int*)  d_in[1];
    const int*   negs    = (const int*)  d_in[2];
    const float* emb_in  = (const float*)d_in[3];
    const float* emb_out = (const float*)d_in[4];
    float*       out     = (float*)d_out;

    const int B = in_sizes[0];              // 16384
    float* partial = (float*)d_ws;          // B floats

    w2v_loss_partial<<<B / 4, 256, 0, stream>>>(target, context, negs,
                                                emb_in, emb_out, partial);
    const float inv_scale = 1.0f / ((float)B * (float)C_DIM);
    w2v_loss_reduce<<<1, 1024, 0, stream>>>(partial, out, B, inv_scale);
}